// Round 5
// baseline (760.436 us; speedup 1.0000x reference)
//
#include <hip/hip_runtime.h>
#include <math.h>

#define HEADS    16
#define HEAD_DIM 88
#define SEQ      577
#define SEQV     640
#define HIDDEN   1408
#define NQKV     4224
#define NQKV_PAD 4352
#define NOUT_PAD 1536
#define RD       44
#define SCALE_F  0.1066003581778052f  // 88^-0.5
#define MPAD_ROWS 18688               // 73 * 256
#define NKT      22                   // HIDDEN / 64 K-tiles
#define BUF_SH   32768                // shorts per LDS buffer (64 KiB)

typedef __attribute__((ext_vector_type(8))) short bf16x8;
typedef __attribute__((ext_vector_type(4))) float f32x4;

__device__ __forceinline__ unsigned short f2bf(float x) {
    unsigned u = __float_as_uint(x);
    unsigned r = u + 0x7fff + ((u >> 16) & 1);
    return (unsigned short)(r >> 16);
}
__device__ __forceinline__ f32x4 fzero() {
    f32x4 z; z.x = 0.f; z.y = 0.f; z.z = 0.f; z.w = 0.f; return z;
}
// bijective XCD swizzle (m204 variant)
__device__ __forceinline__ int xcd_swz(int flat, int nwg) {
    int q = nwg >> 3, r = nwg & 7;
    int x = flat & 7, j = flat >> 3;
    return (x < r ? x * (q + 1) : r * (q + 1) + (x - r) * q) + j;
}

// ---------------------------------------------------------------- rope table
__global__ void rope_precompute(float* __restrict__ cosb, float* __restrict__ sinb) {
    int s = blockIdx.x;
    int j = threadIdx.x;
    if (j >= RD) return;
    float c, sn;
    if (s == SEQ - 1) {
        c = 1.f; sn = 0.f;
    } else {
        int fx = s % 24, fy = s / 24;
        int p = (j < 22) ? j : j - 22;
        float inv = powf(10000.f, -(float)p / 22.f);
        float f = (float)((j < 22 ? fx : fy) + 1) * inv;
        c = cosf(f); sn = sinf(f);
    }
    cosb[s * RD + j] = c;
    sinb[s * RD + j] = sn;
}

// --------------------------------------------------------- fp32 -> bf16 copy
__global__ void conv_hs(const float* __restrict__ in, unsigned short* __restrict__ out,
                        long nreal, long ntot) {
    long i = ((long)blockIdx.x * 256 + threadIdx.x) * 4;
    if (i >= ntot) return;
    ushort4 o;
    if (i < nreal) {
        float4 v = *(const float4*)(in + i);
        o = make_ushort4(f2bf(v.x), f2bf(v.y), f2bf(v.z), f2bf(v.w));
    } else {
        o = make_ushort4(0, 0, 0, 0);
    }
    *(ushort4*)(out + i) = o;
}

// ------------------------------------------- fp32 [R][Creal] -> bf16 [Cpad][R]
__global__ void conv_wT(const float* __restrict__ in, unsigned short* __restrict__ out,
                        int R, int Creal) {
    __shared__ float t[32][33];
    int bx = blockIdx.x * 32, by = blockIdx.y * 32;
    int tx = threadIdx.x & 31, ty = threadIdx.x >> 5;
    #pragma unroll
    for (int i = 0; i < 4; ++i) {
        int col = bx + tx;
        t[ty + i * 8][tx] = (col < Creal) ? in[(size_t)(by + ty + i * 8) * Creal + col] : 0.f;
    }
    __syncthreads();
    #pragma unroll
    for (int i = 0; i < 4; ++i)
        out[(size_t)(bx + ty + i * 8) * R + by + tx] = f2bf(t[tx][ty + i * 8]);
}

// ------------------------------------- stage one 128x64 bf16 half-tile
__device__ __forceinline__ void stage_half(const unsigned short* __restrict__ src,
                                           int kt, unsigned short* lds, int tid) {
    #pragma unroll
    for (int q = 0; q < 2; ++q) {
        int cf = tid + 512 * q;          // 16B-chunk 0..1023; r=cf>>3, c=cf&7
        int r  = cf >> 3, c = cf & 7;
        int cg = c ^ (r & 7);
        __builtin_amdgcn_global_load_lds(
            (const __attribute__((address_space(1))) void*)(src + (size_t)r * HIDDEN + kt * 64 + cg * 8),
            (__attribute__((address_space(3))) void*)(lds + cf * 8),
            16, 0, 0);
    }
}

template<int N> __device__ __forceinline__ void vwait() {
    if constexpr (N >= 0)
        asm volatile("s_waitcnt vmcnt(%0)" :: "i"(N) : "memory");
}

// -------- one 8-phase-template phase: quadrant (IH,JH) of tile in buffer CBUF
template<int CBUF, int IH, int JH, bool STG, int SSIDE, int SHALF, int SBUF, int WAITN>
__device__ __forceinline__ void phase8(
    const unsigned short* __restrict__ wsrc, const unsigned short* __restrict__ hsrc,
    unsigned short* smem, int skt, int tid,
    int ww, int wh, int quad, int l15, f32x4 (&acc)[8][4])
{
    bf16x8 afr[4][2], bfr[2][2];
    #pragma unroll
    for (int i2 = 0; i2 < 4; ++i2)
        #pragma unroll
        for (int kk = 0; kk < 2; ++kk) {
            int r = ww * 64 + i2 * 16 + l15;
            afr[i2][kk] = *(const bf16x8*)(smem + CBUF * BUF_SH + IH * 8192
                          + r * 64 + (((kk * 4 + quad) ^ (r & 7)) << 3));
        }
    #pragma unroll
    for (int j2 = 0; j2 < 2; ++j2)
        #pragma unroll
        for (int kk = 0; kk < 2; ++kk) {
            int r = wh * 32 + j2 * 16 + l15;
            bfr[j2][kk] = *(const bf16x8*)(smem + CBUF * BUF_SH + 16384 + JH * 8192
                          + r * 64 + (((kk * 4 + quad) ^ (r & 7)) << 3));
        }
    if constexpr (STG) {
        const unsigned short* s = (SSIDE ? hsrc : wsrc) + (size_t)SHALF * 128 * HIDDEN;
        stage_half(s, skt, smem + SBUF * BUF_SH + (SSIDE ? 16384 : 0) + SHALF * 8192, tid);
    }
    __builtin_amdgcn_sched_barrier(0);
    __builtin_amdgcn_s_barrier();
    __builtin_amdgcn_sched_barrier(0);
    __builtin_amdgcn_s_setprio(1);
    #pragma unroll
    for (int i2 = 0; i2 < 4; ++i2)
        #pragma unroll
        for (int j2 = 0; j2 < 2; ++j2)
            #pragma unroll
            for (int kk = 0; kk < 2; ++kk)
                acc[IH * 4 + i2][JH * 2 + j2] = __builtin_amdgcn_mfma_f32_16x16x32_bf16(
                    afr[i2][kk], bfr[j2][kk], acc[IH * 4 + i2][JH * 2 + j2], 0, 0, 0);
    __builtin_amdgcn_s_setprio(0);
    __builtin_amdgcn_sched_barrier(0);
    vwait<WAITN>();
    __builtin_amdgcn_s_barrier();
    __builtin_amdgcn_sched_barrier(0);
}

// ------------------------- 256x256xK 8-phase GEMM core (2 K-tiles / 8 phases)
__device__ __forceinline__ void gemm256_8ph(
    const unsigned short* __restrict__ wsrc, const unsigned short* __restrict__ hsrc,
    unsigned short* smem, int tid, f32x4 (&acc)[8][4])
{
    const int lane = tid & 63, w8 = tid >> 6;
    const int quad = lane >> 4, l15 = lane & 15;
    const int ww = w8 >> 2, wh = w8 & 3;

    stage_half(wsrc,                0, smem,                  tid);
    stage_half(hsrc,                0, smem + 16384,          tid);
    stage_half(wsrc + 128 * HIDDEN, 0, smem + 8192,           tid);
    stage_half(hsrc + 128 * HIDDEN, 0, smem + 24576,          tid);
    stage_half(wsrc,                1, smem + BUF_SH,         tid);
    stage_half(hsrc,                1, smem + BUF_SH + 16384, tid);
    asm volatile("s_waitcnt vmcnt(4)" ::: "memory");
    __builtin_amdgcn_s_barrier();
    __builtin_amdgcn_sched_barrier(0);

    for (int it = 0; it < 10; ++it) {
        int k1 = 2 * it + 1, k2 = 2 * it + 2, k3 = 2 * it + 3;
        phase8<0,0,0, true,0,1,1,  6>(wsrc, hsrc, smem, k1, tid, ww, wh, quad, l15, acc);
        phase8<0,0,1, true,1,1,1, -1>(wsrc, hsrc, smem, k1, tid, ww, wh, quad, l15, acc);
        phase8<0,1,0, true,0,0,0, -1>(wsrc, hsrc, smem, k2, tid, ww, wh, quad, l15, acc);
        phase8<0,1,1, true,1,0,0,  8>(wsrc, hsrc, smem, k2, tid, ww, wh, quad, l15, acc);
        phase8<1,0,0, true,0,1,0,  6>(wsrc, hsrc, smem, k2, tid, ww, wh, quad, l15, acc);
        phase8<1,0,1, true,1,1,0, -1>(wsrc, hsrc, smem, k2, tid, ww, wh, quad, l15, acc);
        phase8<1,1,0, true,0,0,1, -1>(wsrc, hsrc, smem, k3, tid, ww, wh, quad, l15, acc);
        phase8<1,1,1, true,1,0,1,  8>(wsrc, hsrc, smem, k3, tid, ww, wh, quad, l15, acc);
    }
    phase8<0,0,0, true,0,1,1,  6>(wsrc, hsrc, smem, 21, tid, ww, wh, quad, l15, acc);
    phase8<0,0,1, true,1,1,1, -1>(wsrc, hsrc, smem, 21, tid, ww, wh, quad, l15, acc);
    phase8<0,1,0, false,0,0,0, -1>(wsrc, hsrc, smem, 0, tid, ww, wh, quad, l15, acc);
    phase8<0,1,1, false,0,0,0,  4>(wsrc, hsrc, smem, 0, tid, ww, wh, quad, l15, acc);
    phase8<1,0,0, false,0,0,0,  0>(wsrc, hsrc, smem, 0, tid, ww, wh, quad, l15, acc);
    phase8<1,0,1, false,0,0,0, -1>(wsrc, hsrc, smem, 0, tid, ww, wh, quad, l15, acc);
    phase8<1,1,0, false,0,0,0, -1>(wsrc, hsrc, smem, 0, tid, ww, wh, quad, l15, acc);
    phase8<1,1,1, false,0,0,0, -1>(wsrc, hsrc, smem, 0, tid, ww, wh, quad, l15, acc);
}

// ---------------------------------------------- QKV: Ct[n][m] = W_t * hs^T
__global__ __launch_bounds__(512, 2) void qkv_mfma(
    const unsigned short* __restrict__ hsb, const unsigned short* __restrict__ wt,
    const float* __restrict__ bias, const float* __restrict__ cosb,
    const float* __restrict__ sinb,
    unsigned short* __restrict__ qb, unsigned short* __restrict__ kb,
    unsigned short* __restrict__ vtb,
    int Mchunk, int row_off)
{
    __shared__ unsigned short smem[2 * BUF_SH];   // 128 KiB
    int tid = threadIdx.x;
    int lane = tid & 63, w8 = tid >> 6;
    int quad = lane >> 4, l15 = lane & 15;
    int ww = w8 >> 2, wh = w8 & 3;

    int nwg  = gridDim.x * gridDim.y;
    int flat = blockIdx.y * gridDim.x + blockIdx.x;
    int wg   = xcd_swz(flat, nwg);
    int n0   = (wg % gridDim.x) * 256;
    int m0   = (wg / gridDim.x) * 256;

    f32x4 acc[8][4];
    #pragma unroll
    for (int i = 0; i < 8; ++i)
        #pragma unroll
        for (int j = 0; j < 4; ++j) acc[i][j] = fzero();

    gemm256_8ph(wt + (size_t)n0 * HIDDEN,
                hsb + (size_t)(row_off + m0) * HIDDEN, smem, tid, acc);

    #pragma unroll
    for (int j = 0; j < 4; ++j) {
        int m = m0 + (j >> 1) * 128 + wh * 32 + (j & 1) * 16 + l15;
        if (m >= Mchunk) continue;
        int bb = m / SEQ;
        int s  = m - bb * SEQ;
        const float* cr = cosb + s * RD;
        const float* sr = sinb + s * RD;
        #pragma unroll
        for (int i = 0; i < 8; ++i) {
            int ng = n0 + (i >> 2) * 128 + ww * 64 + (i & 3) * 16 + quad * 4;
            if (ng >= NQKV) continue;
            int sec = ng / HIDDEN;
            int nn  = ng - sec * HIDDEN;
            int h   = nn / HEAD_DIM;
            int d0  = nn - h * HEAD_DIM;
            int bh  = bb * HEADS + h;
            f32x4 v = acc[i][j];
            const float4 bv = *(const float4*)(bias + ng);
            v.x += bv.x; v.y += bv.y; v.z += bv.z; v.w += bv.w;
            if (sec < 2) {
                int p0 = d0 >> 1;
                float c0 = cr[p0],     s0 = sr[p0];
                float c1 = cr[p0 + 1], s1 = sr[p0 + 1];
                float x0 = v.x, x1 = v.y;
                v.x = x0 * c0 - x1 * s0; v.y = x0 * s0 + x1 * c0;
                x0 = v.z; x1 = v.w;
                v.z = x0 * c1 - x1 * s1; v.w = x0 * s1 + x1 * c1;
                if (sec == 0) { v.x *= SCALE_F; v.y *= SCALE_F; v.z *= SCALE_F; v.w *= SCALE_F; }
                unsigned short* dst = (sec == 0) ? qb : kb;
                ushort4 o = make_ushort4(f2bf(v.x), f2bf(v.y), f2bf(v.z), f2bf(v.w));
                *(ushort4*)(dst + ((size_t)bh * SEQ + s) * HEAD_DIM + d0) = o;
            } else {
                unsigned short* vb = vtb + ((size_t)bh * HEAD_DIM + d0) * SEQV + s;
                vb[0]        = f2bf(v.x);
                vb[SEQV]     = f2bf(v.y);
                vb[2 * SEQV] = f2bf(v.z);
                vb[3 * SEQV] = f2bf(v.w);
            }
        }
    }
}

// ---------------------------------------------- out proj: out = attn @ W_o + b
__global__ __launch_bounds__(512, 2) void out_mfma(
    const unsigned short* __restrict__ ab, const unsigned short* __restrict__ wt,
    const float* __restrict__ bias, float* __restrict__ out,
    int Mchunk, int row_off)
{
    __shared__ unsigned short smem[2 * BUF_SH];   // 128 KiB
    int tid = threadIdx.x;
    int lane = tid & 63, w8 = tid >> 6;
    int quad = lane >> 4, l15 = lane & 15;
    int ww = w8 >> 2, wh = w8 & 3;

    int nwg  = gridDim.x * gridDim.y;
    int flat = blockIdx.y * gridDim.x + blockIdx.x;
    int wg   = xcd_swz(flat, nwg);
    int n0   = (wg % gridDim.x) * 256;
    int m0   = (wg / gridDim.x) * 256;

    f32x4 acc[8][4];
    #pragma unroll
    for (int i = 0; i < 8; ++i)
        #pragma unroll
        for (int j = 0; j < 4; ++j) acc[i][j] = fzero();

    gemm256_8ph(wt + (size_t)n0 * HIDDEN,
                ab + (size_t)m0 * HIDDEN, smem, tid, acc);

    #pragma unroll
    for (int j = 0; j < 4; ++j) {
        int m = m0 + (j >> 1) * 128 + wh * 32 + (j & 1) * 16 + l15;
        if (m >= Mchunk) continue;
        size_t orow = (size_t)(row_off + m) * HIDDEN;
        #pragma unroll
        for (int i = 0; i < 8; ++i) {
            int nn = n0 + (i >> 2) * 128 + ww * 64 + (i & 3) * 16 + quad * 4;
            if (nn >= HIDDEN) continue;
            f32x4 v = acc[i][j];
            const float4 bv = *(const float4*)(bias + nn);
            v.x += bv.x; v.y += bv.y; v.z += bv.z; v.w += bv.w;
            *(f32x4*)(out + orow + nn) = v;
        }
    }
}

// ------------------------------------------------- MFMA flash attention
// ONE WAVE PER BLOCK (64 threads, 32 queries): 19x16x32 = 9728 independent
// waves -> TLP hides L2/LDS/VALU latency (no barriers, no convoys). K/V read
// directly from L2; only wave-private Ps (4.6 KB) in LDS. Swapped QK^T
// (S^T = mfma(K, Q)): query = l15, key = nf*16 + quad*4 + r. 9 full tiles
// (no masking) + 1 masked tail tile (keys 576..639, 1 valid).
#define KTT  64
#define PSTR 72    // Ps row stride (144B, 16B-aligned for b128 reads)
#define RESCALE_THR 8.0f

template<bool FULL>
__device__ __forceinline__ void attn_step(
    int k0, const unsigned short* __restrict__ kg, const unsigned short* __restrict__ vg,
    unsigned short* __restrict__ Ps, int quad, int l15,
    const bf16x8 (&qf)[2][3], f32x4 (&O)[2][6], float (&m_i)[2], float (&l_i)[2])
{
    // K fragments direct from global (L2-hot, shared by all q-waves of bh)
    bf16x8 kf[3][4];
    #pragma unroll
    for (int ks = 0; ks < 3; ++ks)
        #pragma unroll
        for (int nf = 0; nf < 4; ++nf) {
            bf16x8 v = *(const bf16x8*)(kg +
                (size_t)(k0 + nf * 16 + l15) * HEAD_DIM + ks * 32 + quad * 8);
            if (ks == 2 && quad == 3) v = (bf16x8)(short)0;  // cols 88..95 absent
            kf[ks][nf] = v;
        }

    f32x4 sc[2][4];
    #pragma unroll
    for (int mf = 0; mf < 2; ++mf)
        #pragma unroll
        for (int nf = 0; nf < 4; ++nf) sc[mf][nf] = fzero();
    __builtin_amdgcn_s_setprio(1);
    #pragma unroll
    for (int ks = 0; ks < 3; ++ks)
        #pragma unroll
        for (int nf = 0; nf < 4; ++nf) {
            sc[0][nf] = __builtin_amdgcn_mfma_f32_16x16x32_bf16(kf[ks][nf], qf[0][ks], sc[0][nf], 0, 0, 0);
            sc[1][nf] = __builtin_amdgcn_mfma_f32_16x16x32_bf16(kf[ks][nf], qf[1][ks], sc[1][nf], 0, 0, 0);
        }
    __builtin_amdgcn_s_setprio(0);

    bf16x8 vf[2][6];
    auto smx = [&](int mf) {
        // tree max (depth 4 + 2 shuffles)
        float t[4];
        #pragma unroll
        for (int nf = 0; nf < 4; ++nf) {
            float mv[4];
            #pragma unroll
            for (int r = 0; r < 4; ++r) {
                bool valid = FULL || (k0 + nf * 16 + quad * 4 + r < SEQ);
                mv[r] = valid ? sc[mf][nf][r] : -INFINITY;
            }
            t[nf] = fmaxf(fmaxf(mv[0], mv[1]), fmaxf(mv[2], mv[3]));
        }
        float pmax = fmaxf(fmaxf(t[0], t[1]), fmaxf(t[2], t[3]));
        pmax = fmaxf(pmax, __shfl_xor(pmax, 16));
        pmax = fmaxf(pmax, __shfl_xor(pmax, 32));
        float mold = m_i[mf];
        bool skip = __all(pmax - mold <= RESCALE_THR);   // T13 defer-max
        float mnew = skip ? mold : fmaxf(mold, pmax);
        float rsum = 0.f;
        #pragma unroll
        for (int nf = 0; nf < 4; ++nf) {
            ushort4 o;
            float s0 = 0.f, s1 = 0.f;
            #pragma unroll
            for (int r = 0; r < 4; ++r) {
                bool valid = FULL || (k0 + nf * 16 + quad * 4 + r < SEQ);
                float p = valid ? __expf(sc[mf][nf][r] - mnew) : 0.f;
                if (r < 2) s0 += p; else s1 += p;
                ((unsigned short*)&o)[r] = f2bf(p);
            }
            rsum += s0 + s1;
            // lane writes 4 consecutive keys of its query's row: one b64
            *(ushort4*)(Ps + (mf * 16 + l15) * PSTR + nf * 16 + quad * 4) = o;
        }
        rsum += __shfl_xor(rsum, 16);
        rsum += __shfl_xor(rsum, 32);
        if (!skip) {
            float alpha = __expf(mold - mnew);
            m_i[mf] = mnew;
            l_i[mf] = l_i[mf] * alpha + rsum;
            #pragma unroll
            for (int r = 0; r < 4; ++r) {
                float ar = __shfl(alpha, quad * 4 + r, 16);  // alpha of query quad*4+r
                #pragma unroll
                for (int nf = 0; nf < 6; ++nf) O[mf][nf][r] *= ar;
            }
        } else {
            l_i[mf] += rsum;
        }
    };

    smx(0);
    #pragma unroll
    for (int ks = 0; ks < 2; ++ks)
        #pragma unroll
        for (int nf = 0; nf < 6; ++nf)
            vf[ks][nf] = *(const bf16x8*)(vg +
                (size_t)(nf * 16 + l15) * SEQV + k0 + ks * 32 + quad * 8);
    smx(1);

    // PV: A = Ps rows (queries), B = V fragments (d-major)
    __builtin_amdgcn_s_setprio(1);
    #pragma unroll
    for (int ks = 0; ks < 2; ++ks) {
        bf16x8 a0 = *(const bf16x8*)(Ps + l15 * PSTR + ks * 32 + quad * 8);
        bf16x8 a1 = *(const bf16x8*)(Ps + (16 + l15) * PSTR + ks * 32 + quad * 8);
        #pragma unroll
        for (int nf = 0; nf < 6; ++nf) {
            O[0][nf] = __builtin_amdgcn_mfma_f32_16x16x32_bf16(a0, vf[ks][nf], O[0][nf], 0, 0, 0);
            O[1][nf] = __builtin_amdgcn_mfma_f32_16x16x32_bf16(a1, vf[ks][nf], O[1][nf], 0, 0, 0);
        }
    }
    __builtin_amdgcn_s_setprio(0);
}

__global__ __launch_bounds__(64, 3) void attn_mfma(
    const unsigned short* __restrict__ qb, const unsigned short* __restrict__ kb,
    const unsigned short* __restrict__ vtb, unsigned short* __restrict__ awsb)
{
    __shared__ unsigned short Ps[32 * PSTR];    // 4.6 KB, wave-private

    int lane = threadIdx.x;
    int quad = lane >> 4, l15 = lane & 15;

    int nwg  = gridDim.x * gridDim.y * gridDim.z;
    int flat = (blockIdx.z * gridDim.y + blockIdx.y) * gridDim.x + blockIdx.x;
    int w    = xcd_swz(flat, nwg);
    int qblk = w % gridDim.x;
    int rem  = w / gridDim.x;
    int h    = rem % gridDim.y;
    int bb   = rem / gridDim.y;
    int q0   = qblk * 32;
    int bh   = bb * HEADS + h;
    const unsigned short* qg = qb  + (size_t)bh * SEQ * HEAD_DIM;
    const unsigned short* kg = kb  + (size_t)bh * SEQ * HEAD_DIM;
    const unsigned short* vg = vtb + (size_t)bh * HEAD_DIM * SEQV;

    bf16x8 qf[2][3];
    #pragma unroll
    for (int mf = 0; mf < 2; ++mf)
        #pragma unroll
        for (int ks = 0; ks < 3; ++ks)
            qf[mf][ks] = *(const bf16x8*)(qg +
                (size_t)(q0 + mf * 16 + l15) * HEAD_DIM + ks * 32 + quad * 8);

    f32x4 O[2][6];
    float m_i[2], l_i[2];
    #pragma unroll
    for (int mf = 0; mf < 2; ++mf) {
        #pragma unroll
        for (int nf = 0; nf < 6; ++nf) O[mf][nf] = fzero();
        m_i[mf] = -INFINITY; l_i[mf] = 0.f;
    }

    // 9 full tiles (keys 0..575, no masking), then masked tail (key 576)
    for (int k0 = 0; k0 < SEQ - KTT; k0 += KTT)
        attn_step<true>(k0, kg, vg, Ps, quad, l15, qf, O, m_i, l_i);
    attn_step<false>(576, kg, vg, Ps, quad, l15, qf, O, m_i, l_i);

    #pragma unroll
    for (int mf = 0; mf < 2; ++mf) {
        #pragma unroll
        for (int r = 0; r < 4; ++r) {
            int row = q0 + mf * 16 + quad * 4 + r;
            if (row >= SEQ) continue;
            float lb = __shfl(l_i[mf], quad * 4 + r, 16);
            float il = 1.f / lb;
            size_t base = (size_t)(bb * SEQ + row) * HIDDEN + h * HEAD_DIM;
            #pragma unroll
            for (int nf = 0; nf < 6; ++nf) {
                int d = nf * 16 + l15;
                if (d < HEAD_DIM)
                    awsb[base + d] = f2bf(O[mf][nf][r] * il);
            }
        }
    }
}

// ---------------------------------------------------------------- launcher
extern "C" void kernel_launch(void* const* d_in, const int* in_sizes, int n_in,
                              void* d_out, int out_size, void* d_ws, size_t ws_size,
                              hipStream_t stream) {
    const float* hs    = (const float*)d_in[0];
    const float* w_qkv = (const float*)d_in[1];
    const float* b_qkv = (const float*)d_in[2];
    const float* w_o   = (const float*)d_in[3];
    const float* b_o   = (const float*)d_in[4];
    float* out = (float*)d_out;

    char* p = (char*)d_ws;
    auto alloc = [&](size_t bytes) {
        char* r = p; p += (bytes + 255) & ~(size_t)255; return r;
    };
    float*          cosb   = (float*)alloc((size_t)SEQ * RD * 4);
    float*          sinb   = (float*)alloc((size_t)SEQ * RD * 4);
    unsigned short* wqkv_t = (unsigned short*)alloc((size_t)NQKV_PAD * HIDDEN * 2);
    unsigned short* wo_t   = (unsigned short*)alloc((size_t)NOUT_PAD * HIDDEN * 2);
    unsigned short* hs_bf  = (unsigned short*)alloc((size_t)MPAD_ROWS * HIDDEN * 2);
    size_t fixed = (size_t)(p - (char*)d_ws);

    size_t per_batch = 2ull * HEADS * SEQ * HEAD_DIM * 2
                     + (size_t)HEADS * HEAD_DIM * SEQV * 2
                     + (size_t)SEQ * HIDDEN * 2;
    size_t pads = 2ull * 128 * HEAD_DIM * 2 + 24ull * SEQV * 2 + 256ull * HIDDEN * 2 + 16 * 256;
    size_t rem = (ws_size > fixed + pads) ? ws_size - fixed - pads : 0;
    int CB = (int)(rem / per_batch);
    if (CB < 1) CB = 1;
    if (CB > 32) CB = 32;

    unsigned short* qbuf  = (unsigned short*)alloc(((size_t)CB * HEADS * SEQ + 128) * HEAD_DIM * 2);
    unsigned short* kbuf  = (unsigned short*)alloc(((size_t)CB * HEADS * SEQ + 128) * HEAD_DIM * 2);
    unsigned short* vtbuf = (unsigned short*)alloc(((size_t)CB * HEADS * HEAD_DIM + 24) * SEQV * 2);
    unsigned short* awsb  = (unsigned short*)alloc(((size_t)CB * SEQ + 256) * HIDDEN * 2);

    rope_precompute<<<dim3(SEQ), dim3(64), 0, stream>>>(cosb, sinb);

    long nreal = (long)32 * SEQ * HIDDEN;
    long ntot  = (long)MPAD_ROWS * HIDDEN;
    conv_hs<<<dim3((unsigned)((ntot / 4 + 255) / 256)), 256, 0, stream>>>(hs, hs_bf, nreal, ntot);
    conv_wT<<<dim3(NQKV_PAD / 32, HIDDEN / 32), 256, 0, stream>>>(w_qkv, wqkv_t, HIDDEN, NQKV);
    conv_wT<<<dim3(NOUT_PAD / 32, HIDDEN / 32), 256, 0, stream>>>(w_o, wo_t, HIDDEN, HIDDEN);

    for (int b_off = 0; b_off < 32; b_off += CB) {
        int nb = (32 - b_off < CB) ? (32 - b_off) : CB;
        int M = nb * SEQ;

        dim3 g1(NQKV_PAD / 256, (M + 255) / 256);
        qkv_mfma<<<g1, 512, 0, stream>>>(hs_bf, wqkv_t, b_qkv, cosb, sinb,
                                         qbuf, kbuf, vtbuf, M, b_off * SEQ);
        dim3 g2((SEQ + 31) / 32, HEADS, nb);
        attn_mfma<<<g2, 64, 0, stream>>>(qbuf, kbuf, vtbuf, awsb);
        dim3 g3(NOUT_PAD / 256, (M + 255) / 256);
        out_mfma<<<g3, 512, 0, stream>>>(awsb, wo_t, b_o, out, M, b_off * SEQ);
    }
}

// Round 6
// 707.626 us; speedup vs baseline: 1.0746x; 1.0746x over previous
//
#include <hip/hip_runtime.h>
#include <math.h>

#define HEADS    16
#define HEAD_DIM 88
#define SEQ      577
#define SEQV     640
#define HIDDEN   1408
#define NQKV     4224
#define NQKV_PAD 4352
#define NOUT_PAD 1536
#define RD       44
#define SCALE_F  0.1066003581778052f  // 88^-0.5
#define MPAD_ROWS 18688               // 73 * 256
#define NKT      22                   // HIDDEN / 64 K-tiles
#define BUF_SH   32768                // shorts per LDS buffer (64 KiB)
#define FR_TILE  6144                 // shorts per fragment tile (K': 3*4*512, V': 2*6*512)
#define FR_BH    61440                // 10 tiles * FR_TILE per (b,h)

typedef __attribute__((ext_vector_type(8))) short bf16x8;
typedef __attribute__((ext_vector_type(4))) float f32x4;

__device__ __forceinline__ unsigned short f2bf(float x) {
    unsigned u = __float_as_uint(x);
    unsigned r = u + 0x7fff + ((u >> 16) & 1);
    return (unsigned short)(r >> 16);
}
__device__ __forceinline__ f32x4 fzero() {
    f32x4 z; z.x = 0.f; z.y = 0.f; z.z = 0.f; z.w = 0.f; return z;
}
// bijective XCD swizzle (m204 variant)
__device__ __forceinline__ int xcd_swz(int flat, int nwg) {
    int q = nwg >> 3, r = nwg & 7;
    int x = flat & 7, j = flat >> 3;
    return (x < r ? x * (q + 1) : r * (q + 1) + (x - r) * q) + j;
}

// ---------------------------------------------------------------- rope table
__global__ void rope_precompute(float* __restrict__ cosb, float* __restrict__ sinb) {
    int s = blockIdx.x;
    int j = threadIdx.x;
    if (j >= RD) return;
    float c, sn;
    if (s == SEQ - 1) {
        c = 1.f; sn = 0.f;
    } else {
        int fx = s % 24, fy = s / 24;
        int p = (j < 22) ? j : j - 22;
        float inv = powf(10000.f, -(float)p / 22.f);
        float f = (float)((j < 22 ? fx : fy) + 1) * inv;
        c = cosf(f); sn = sinf(f);
    }
    cosb[s * RD + j] = c;
    sinb[s * RD + j] = sn;
}

// --------------------------------------------------------- fp32 -> bf16 copy
__global__ void conv_hs(const float* __restrict__ in, unsigned short* __restrict__ out,
                        long nreal, long ntot) {
    long i = ((long)blockIdx.x * 256 + threadIdx.x) * 4;
    if (i >= ntot) return;
    ushort4 o;
    if (i < nreal) {
        float4 v = *(const float4*)(in + i);
        o = make_ushort4(f2bf(v.x), f2bf(v.y), f2bf(v.z), f2bf(v.w));
    } else {
        o = make_ushort4(0, 0, 0, 0);
    }
    *(ushort4*)(out + i) = o;
}

// ------------------------------------------- fp32 [R][Creal] -> bf16 [Cpad][R]
__global__ void conv_wT(const float* __restrict__ in, unsigned short* __restrict__ out,
                        int R, int Creal) {
    __shared__ float t[32][33];
    int bx = blockIdx.x * 32, by = blockIdx.y * 32;
    int tx = threadIdx.x & 31, ty = threadIdx.x >> 5;
    #pragma unroll
    for (int i = 0; i < 4; ++i) {
        int col = bx + tx;
        t[ty + i * 8][tx] = (col < Creal) ? in[(size_t)(by + ty + i * 8) * Creal + col] : 0.f;
    }
    __syncthreads();
    #pragma unroll
    for (int i = 0; i < 4; ++i)
        out[(size_t)(bx + ty + i * 8) * R + by + tx] = f2bf(t[tx][ty + i * 8]);
}

// ------------------------------------- stage one 128x64 bf16 half-tile
__device__ __forceinline__ void stage_half(const unsigned short* __restrict__ src,
                                           int kt, unsigned short* lds, int tid) {
    #pragma unroll
    for (int q = 0; q < 2; ++q) {
        int cf = tid + 512 * q;          // 16B-chunk 0..1023; r=cf>>3, c=cf&7
        int r  = cf >> 3, c = cf & 7;
        int cg = c ^ (r & 7);
        __builtin_amdgcn_global_load_lds(
            (const __attribute__((address_space(1))) void*)(src + (size_t)r * HIDDEN + kt * 64 + cg * 8),
            (__attribute__((address_space(3))) void*)(lds + cf * 8),
            16, 0, 0);
    }
}

template<int N> __device__ __forceinline__ void vwait() {
    if constexpr (N >= 0)
        asm volatile("s_waitcnt vmcnt(%0)" :: "i"(N) : "memory");
}

// -------- one 8-phase-template phase: quadrant (IH,JH) of tile in buffer CBUF
template<int CBUF, int IH, int JH, bool STG, int SSIDE, int SHALF, int SBUF, int WAITN>
__device__ __forceinline__ void phase8(
    const unsigned short* __restrict__ wsrc, const unsigned short* __restrict__ hsrc,
    unsigned short* smem, int skt, int tid,
    int ww, int wh, int quad, int l15, f32x4 (&acc)[8][4])
{
    bf16x8 afr[4][2], bfr[2][2];
    #pragma unroll
    for (int i2 = 0; i2 < 4; ++i2)
        #pragma unroll
        for (int kk = 0; kk < 2; ++kk) {
            int r = ww * 64 + i2 * 16 + l15;
            afr[i2][kk] = *(const bf16x8*)(smem + CBUF * BUF_SH + IH * 8192
                          + r * 64 + (((kk * 4 + quad) ^ (r & 7)) << 3));
        }
    #pragma unroll
    for (int j2 = 0; j2 < 2; ++j2)
        #pragma unroll
        for (int kk = 0; kk < 2; ++kk) {
            int r = wh * 32 + j2 * 16 + l15;
            bfr[j2][kk] = *(const bf16x8*)(smem + CBUF * BUF_SH + 16384 + JH * 8192
                          + r * 64 + (((kk * 4 + quad) ^ (r & 7)) << 3));
        }
    if constexpr (STG) {
        const unsigned short* s = (SSIDE ? hsrc : wsrc) + (size_t)SHALF * 128 * HIDDEN;
        stage_half(s, skt, smem + SBUF * BUF_SH + (SSIDE ? 16384 : 0) + SHALF * 8192, tid);
    }
    __builtin_amdgcn_sched_barrier(0);
    __builtin_amdgcn_s_barrier();
    __builtin_amdgcn_sched_barrier(0);
    __builtin_amdgcn_s_setprio(1);
    #pragma unroll
    for (int i2 = 0; i2 < 4; ++i2)
        #pragma unroll
        for (int j2 = 0; j2 < 2; ++j2)
            #pragma unroll
            for (int kk = 0; kk < 2; ++kk)
                acc[IH * 4 + i2][JH * 2 + j2] = __builtin_amdgcn_mfma_f32_16x16x32_bf16(
                    afr[i2][kk], bfr[j2][kk], acc[IH * 4 + i2][JH * 2 + j2], 0, 0, 0);
    __builtin_amdgcn_s_setprio(0);
    __builtin_amdgcn_sched_barrier(0);
    vwait<WAITN>();
    __builtin_amdgcn_s_barrier();
    __builtin_amdgcn_sched_barrier(0);
}

// ------------------------- 256x256xK 8-phase GEMM core (2 K-tiles / 8 phases)
__device__ __forceinline__ void gemm256_8ph(
    const unsigned short* __restrict__ wsrc, const unsigned short* __restrict__ hsrc,
    unsigned short* smem, int tid, f32x4 (&acc)[8][4])
{
    const int lane = tid & 63, w8 = tid >> 6;
    const int quad = lane >> 4, l15 = lane & 15;
    const int ww = w8 >> 2, wh = w8 & 3;

    stage_half(wsrc,                0, smem,                  tid);
    stage_half(hsrc,                0, smem + 16384,          tid);
    stage_half(wsrc + 128 * HIDDEN, 0, smem + 8192,           tid);
    stage_half(hsrc + 128 * HIDDEN, 0, smem + 24576,          tid);
    stage_half(wsrc,                1, smem + BUF_SH,         tid);
    stage_half(hsrc,                1, smem + BUF_SH + 16384, tid);
    asm volatile("s_waitcnt vmcnt(4)" ::: "memory");
    __builtin_amdgcn_s_barrier();
    __builtin_amdgcn_sched_barrier(0);

    for (int it = 0; it < 10; ++it) {
        int k1 = 2 * it + 1, k2 = 2 * it + 2, k3 = 2 * it + 3;
        phase8<0,0,0, true,0,1,1,  6>(wsrc, hsrc, smem, k1, tid, ww, wh, quad, l15, acc);
        phase8<0,0,1, true,1,1,1, -1>(wsrc, hsrc, smem, k1, tid, ww, wh, quad, l15, acc);
        phase8<0,1,0, true,0,0,0, -1>(wsrc, hsrc, smem, k2, tid, ww, wh, quad, l15, acc);
        phase8<0,1,1, true,1,0,0,  8>(wsrc, hsrc, smem, k2, tid, ww, wh, quad, l15, acc);
        phase8<1,0,0, true,0,1,0,  6>(wsrc, hsrc, smem, k2, tid, ww, wh, quad, l15, acc);
        phase8<1,0,1, true,1,1,0, -1>(wsrc, hsrc, smem, k2, tid, ww, wh, quad, l15, acc);
        phase8<1,1,0, true,0,0,1, -1>(wsrc, hsrc, smem, k3, tid, ww, wh, quad, l15, acc);
        phase8<1,1,1, true,1,0,1,  8>(wsrc, hsrc, smem, k3, tid, ww, wh, quad, l15, acc);
    }
    phase8<0,0,0, true,0,1,1,  6>(wsrc, hsrc, smem, 21, tid, ww, wh, quad, l15, acc);
    phase8<0,0,1, true,1,1,1, -1>(wsrc, hsrc, smem, 21, tid, ww, wh, quad, l15, acc);
    phase8<0,1,0, false,0,0,0, -1>(wsrc, hsrc, smem, 0, tid, ww, wh, quad, l15, acc);
    phase8<0,1,1, false,0,0,0,  4>(wsrc, hsrc, smem, 0, tid, ww, wh, quad, l15, acc);
    phase8<1,0,0, false,0,0,0,  0>(wsrc, hsrc, smem, 0, tid, ww, wh, quad, l15, acc);
    phase8<1,0,1, false,0,0,0, -1>(wsrc, hsrc, smem, 0, tid, ww, wh, quad, l15, acc);
    phase8<1,1,0, false,0,0,0, -1>(wsrc, hsrc, smem, 0, tid, ww, wh, quad, l15, acc);
    phase8<1,1,1, false,0,0,0, -1>(wsrc, hsrc, smem, 0, tid, ww, wh, quad, l15, acc);
}

// ---------------------------------------------- QKV: Ct[n][m] = W_t * hs^T
// K and V outputs are scattered into MFMA-fragment order so attn's loads are
// perfectly coalesced:
//   K'[bh][kt][ks(3)][nf(4)][lane(64)][8] : K[key=kt*64+nf*16+l15][d=ks*32+quad*8+j]
//   V'[bh][kt][ks(2)][nf(6)][lane(64)][8] : V[key=kt*64+ks*32+quad*8+j][d=nf*16+l15]
__global__ __launch_bounds__(512, 2) void qkv_mfma(
    const unsigned short* __restrict__ hsb, const unsigned short* __restrict__ wt,
    const float* __restrict__ bias, const float* __restrict__ cosb,
    const float* __restrict__ sinb,
    unsigned short* __restrict__ qb, unsigned short* __restrict__ kfr,
    unsigned short* __restrict__ vfr,
    int Mchunk, int row_off)
{
    __shared__ unsigned short smem[2 * BUF_SH];   // 128 KiB
    int tid = threadIdx.x;
    int lane = tid & 63, w8 = tid >> 6;
    int quad = lane >> 4, l15 = lane & 15;
    int ww = w8 >> 2, wh = w8 & 3;

    int nwg  = gridDim.x * gridDim.y;
    int flat = blockIdx.y * gridDim.x + blockIdx.x;
    int wg   = xcd_swz(flat, nwg);
    int n0   = (wg % gridDim.x) * 256;
    int m0   = (wg / gridDim.x) * 256;

    f32x4 acc[8][4];
    #pragma unroll
    for (int i = 0; i < 8; ++i)
        #pragma unroll
        for (int j = 0; j < 4; ++j) acc[i][j] = fzero();

    gemm256_8ph(wt + (size_t)n0 * HIDDEN,
                hsb + (size_t)(row_off + m0) * HIDDEN, smem, tid, acc);

    #pragma unroll
    for (int j = 0; j < 4; ++j) {
        int m = m0 + (j >> 1) * 128 + wh * 32 + (j & 1) * 16 + l15;
        if (m >= Mchunk) continue;
        int bb = m / SEQ;
        int s  = m - bb * SEQ;
        const float* cr = cosb + s * RD;
        const float* sr = sinb + s * RD;
        int kt = s >> 6, sk = s & 63;
        #pragma unroll
        for (int i = 0; i < 8; ++i) {
            int ng = n0 + (i >> 2) * 128 + ww * 64 + (i & 3) * 16 + quad * 4;
            if (ng >= NQKV) continue;
            int sec = ng / HIDDEN;
            int nn  = ng - sec * HIDDEN;
            int h   = nn / HEAD_DIM;
            int d0  = nn - h * HEAD_DIM;
            int bh  = bb * HEADS + h;
            f32x4 v = acc[i][j];
            const float4 bv = *(const float4*)(bias + ng);
            v.x += bv.x; v.y += bv.y; v.z += bv.z; v.w += bv.w;
            if (sec < 2) {
                int p0 = d0 >> 1;
                float c0 = cr[p0],     s0 = sr[p0];
                float c1 = cr[p0 + 1], s1 = sr[p0 + 1];
                float x0 = v.x, x1 = v.y;
                v.x = x0 * c0 - x1 * s0; v.y = x0 * s0 + x1 * c0;
                x0 = v.z; x1 = v.w;
                v.z = x0 * c1 - x1 * s1; v.w = x0 * s1 + x1 * c1;
                if (sec == 0) {
                    v.x *= SCALE_F; v.y *= SCALE_F; v.z *= SCALE_F; v.w *= SCALE_F;
                    ushort4 o = make_ushort4(f2bf(v.x), f2bf(v.y), f2bf(v.z), f2bf(v.w));
                    *(ushort4*)(qb + ((size_t)bh * SEQ + s) * HEAD_DIM + d0) = o;
                } else {
                    ushort4 o = make_ushort4(f2bf(v.x), f2bf(v.y), f2bf(v.z), f2bf(v.w));
                    size_t ka = ((((size_t)bh * 10 + kt) * 3 + (d0 >> 5)) * 4 + (sk >> 4)) * 512
                              + (size_t)(((((d0 >> 3) & 3) << 4) + (sk & 15)) << 3) + (d0 & 7);
                    *(ushort4*)(kfr + ka) = o;
                }
            } else {
                size_t vb0 = ((((size_t)bh * 10 + kt) * 2 + (sk >> 5)) * 6) * 512
                           + (size_t)((((sk >> 3) & 3) << 4) << 3) + (sk & 7);
                int d;
                d = d0;     vfr[vb0 + ((d >> 4) << 9) + ((d & 15) << 3)] = f2bf(v.x);
                d = d0 + 1; vfr[vb0 + ((d >> 4) << 9) + ((d & 15) << 3)] = f2bf(v.y);
                d = d0 + 2; vfr[vb0 + ((d >> 4) << 9) + ((d & 15) << 3)] = f2bf(v.z);
                d = d0 + 3; vfr[vb0 + ((d >> 4) << 9) + ((d & 15) << 3)] = f2bf(v.w);
            }
        }
    }
}

// ---------------------------------------------- out proj: out = attn @ W_o + b
__global__ __launch_bounds__(512, 2) void out_mfma(
    const unsigned short* __restrict__ ab, const unsigned short* __restrict__ wt,
    const float* __restrict__ bias, float* __restrict__ out,
    int Mchunk, int row_off)
{
    __shared__ unsigned short smem[2 * BUF_SH];   // 128 KiB
    int tid = threadIdx.x;
    int lane = tid & 63, w8 = tid >> 6;
    int quad = lane >> 4, l15 = lane & 15;
    int ww = w8 >> 2, wh = w8 & 3;

    int nwg  = gridDim.x * gridDim.y;
    int flat = blockIdx.y * gridDim.x + blockIdx.x;
    int wg   = xcd_swz(flat, nwg);
    int n0   = (wg % gridDim.x) * 256;
    int m0   = (wg / gridDim.x) * 256;

    f32x4 acc[8][4];
    #pragma unroll
    for (int i = 0; i < 8; ++i)
        #pragma unroll
        for (int j = 0; j < 4; ++j) acc[i][j] = fzero();

    gemm256_8ph(wt + (size_t)n0 * HIDDEN,
                ab + (size_t)m0 * HIDDEN, smem, tid, acc);

    #pragma unroll
    for (int j = 0; j < 4; ++j) {
        int m = m0 + (j >> 1) * 128 + wh * 32 + (j & 1) * 16 + l15;
        if (m >= Mchunk) continue;
        size_t orow = (size_t)(row_off + m) * HIDDEN;
        #pragma unroll
        for (int i = 0; i < 8; ++i) {
            int nn = n0 + (i >> 2) * 128 + ww * 64 + (i & 3) * 16 + quad * 4;
            if (nn >= HIDDEN) continue;
            f32x4 v = acc[i][j];
            const float4 bv = *(const float4*)(bias + nn);
            v.x += bv.x; v.y += bv.y; v.z += bv.z; v.w += bv.w;
            *(f32x4*)(out + orow + nn) = v;
        }
    }
}

// ------------------------------------------------- MFMA flash attention
// ONE WAVE PER BLOCK (64 threads, 32 queries). K/V read from PRE-FRAGMENTED
// global layouts: every load is base + group*512 + lane*8 -> fully coalesced
// 1 KB/instruction (8 L2 lines, zero amplification). Only wave-private Ps in
// LDS; no barriers. Swapped QK^T: query = l15, key = nf*16 + quad*4 + r.
// 9 full tiles + 1 tail tile (key 576 valid; V tail zero-masked in-register).
#define KTT  64
#define PSTR 72    // Ps row stride (144B, 16B-aligned for b128 reads)
#define RESCALE_THR 8.0f

template<bool FULL>
__device__ __forceinline__ void attn_step(
    int k0, const unsigned short* __restrict__ kg, const unsigned short* __restrict__ vg,
    unsigned short* __restrict__ Ps, int lane, int quad, int l15,
    const bf16x8 (&qf)[2][3], f32x4 (&O)[2][6], float (&m_i)[2], float (&l_i)[2])
{
    const int kt = k0 >> 6;
    const unsigned short* kbase = kg + (size_t)kt * FR_TILE + lane * 8;
    const unsigned short* vbase = vg + (size_t)kt * FR_TILE + lane * 8;

    // K fragments: coalesced (group-major, lane-minor)
    bf16x8 kf[3][4];
    #pragma unroll
    for (int ks = 0; ks < 3; ++ks)
        #pragma unroll
        for (int nf = 0; nf < 4; ++nf) {
            bf16x8 v = *(const bf16x8*)(kbase + ((ks * 4 + nf) << 9));
            if (ks == 2 && quad == 3) v = (bf16x8)(short)0;  // d 88..95 absent
            kf[ks][nf] = v;
        }

    f32x4 sc[2][4];
    #pragma unroll
    for (int mf = 0; mf < 2; ++mf)
        #pragma unroll
        for (int nf = 0; nf < 4; ++nf) sc[mf][nf] = fzero();
    __builtin_amdgcn_s_setprio(1);
    #pragma unroll
    for (int ks = 0; ks < 3; ++ks)
        #pragma unroll
        for (int nf = 0; nf < 4; ++nf) {
            sc[0][nf] = __builtin_amdgcn_mfma_f32_16x16x32_bf16(kf[ks][nf], qf[0][ks], sc[0][nf], 0, 0, 0);
            sc[1][nf] = __builtin_amdgcn_mfma_f32_16x16x32_bf16(kf[ks][nf], qf[1][ks], sc[1][nf], 0, 0, 0);
        }
    __builtin_amdgcn_s_setprio(0);

    // V fragments issued now (kf dead): latency hides under both softmax halves
    bf16x8 vf[2][6];
    #pragma unroll
    for (int ks = 0; ks < 2; ++ks)
        #pragma unroll
        for (int nf = 0; nf < 6; ++nf) {
            bf16x8 v = *(const bf16x8*)(vbase + ((ks * 6 + nf) << 9));
            if constexpr (!FULL) {
                // tail: keys 577..639 never written -> zero-mask garbage
                if (ks == 0 && quad == 0) {
                    bf16x8 z = (bf16x8)(short)0;
                    z[0] = v[0];           // key 576 (j=0) is the only valid one
                    v = z;
                } else {
                    v = (bf16x8)(short)0;
                }
            }
            vf[ks][nf] = v;
        }

    auto smx = [&](int mf) {
        float t[4];
        #pragma unroll
        for (int nf = 0; nf < 4; ++nf) {
            float mv[4];
            #pragma unroll
            for (int r = 0; r < 4; ++r) {
                bool valid = FULL || (k0 + nf * 16 + quad * 4 + r < SEQ);
                mv[r] = valid ? sc[mf][nf][r] : -INFINITY;
            }
            t[nf] = fmaxf(fmaxf(mv[0], mv[1]), fmaxf(mv[2], mv[3]));
        }
        float pmax = fmaxf(fmaxf(t[0], t[1]), fmaxf(t[2], t[3]));
        pmax = fmaxf(pmax, __shfl_xor(pmax, 16));
        pmax = fmaxf(pmax, __shfl_xor(pmax, 32));
        float mold = m_i[mf];
        bool skip = __all(pmax - mold <= RESCALE_THR);   // T13 defer-max
        float mnew = skip ? mold : fmaxf(mold, pmax);
        float rsum = 0.f;
        #pragma unroll
        for (int nf = 0; nf < 4; ++nf) {
            ushort4 o;
            float s0 = 0.f, s1 = 0.f;
            #pragma unroll
            for (int r = 0; r < 4; ++r) {
                bool valid = FULL || (k0 + nf * 16 + quad * 4 + r < SEQ);
                float p = valid ? __expf(sc[mf][nf][r] - mnew) : 0.f;
                if (r < 2) s0 += p; else s1 += p;
                ((unsigned short*)&o)[r] = f2bf(p);
            }
            rsum += s0 + s1;
            *(ushort4*)(Ps + (mf * 16 + l15) * PSTR + nf * 16 + quad * 4) = o;
        }
        rsum += __shfl_xor(rsum, 16);
        rsum += __shfl_xor(rsum, 32);
        if (!skip) {
            float alpha = __expf(mold - mnew);
            m_i[mf] = mnew;
            l_i[mf] = l_i[mf] * alpha + rsum;
            #pragma unroll
            for (int r = 0; r < 4; ++r) {
                float ar = __shfl(alpha, quad * 4 + r, 16);
                #pragma unroll
                for (int nf = 0; nf < 6; ++nf) O[mf][nf][r] *= ar;
            }
        } else {
            l_i[mf] += rsum;
        }
    };

    smx(0);
    smx(1);

    // PV: A = Ps rows (queries), B = V fragments (d-major)
    __builtin_amdgcn_s_setprio(1);
    #pragma unroll
    for (int ks = 0; ks < 2; ++ks) {
        bf16x8 a0 = *(const bf16x8*)(Ps + l15 * PSTR + ks * 32 + quad * 8);
        bf16x8 a1 = *(const bf16x8*)(Ps + (16 + l15) * PSTR + ks * 32 + quad * 8);
        #pragma unroll
        for (int nf = 0; nf < 6; ++nf) {
            O[0][nf] = __builtin_amdgcn_mfma_f32_16x16x32_bf16(a0, vf[ks][nf], O[0][nf], 0, 0, 0);
            O[1][nf] = __builtin_amdgcn_mfma_f32_16x16x32_bf16(a1, vf[ks][nf], O[1][nf], 0, 0, 0);
        }
    }
    __builtin_amdgcn_s_setprio(0);
}

__global__ __launch_bounds__(64, 3) void attn_mfma(
    const unsigned short* __restrict__ qb, const unsigned short* __restrict__ kfr,
    const unsigned short* __restrict__ vfr, unsigned short* __restrict__ awsb)
{
    __shared__ unsigned short Ps[32 * PSTR];    // 4.6 KB, wave-private

    int lane = threadIdx.x;
    int quad = lane >> 4, l15 = lane & 15;

    int nwg  = gridDim.x * gridDim.y * gridDim.z;
    int flat = (blockIdx.z * gridDim.y + blockIdx.y) * gridDim.x + blockIdx.x;
    int w    = xcd_swz(flat, nwg);
    int qblk = w % gridDim.x;
    int rem  = w / gridDim.x;
    int h    = rem % gridDim.y;
    int bb   = rem / gridDim.y;
    int q0   = qblk * 32;
    int bh   = bb * HEADS + h;
    const unsigned short* qg = qb  + (size_t)bh * SEQ * HEAD_DIM;
    const unsigned short* kg = kfr + (size_t)bh * FR_BH;
    const unsigned short* vg = vfr + (size_t)bh * FR_BH;

    bf16x8 qf[2][3];
    #pragma unroll
    for (int mf = 0; mf < 2; ++mf)
        #pragma unroll
        for (int ks = 0; ks < 3; ++ks)
            qf[mf][ks] = *(const bf16x8*)(qg +
                (size_t)(q0 + mf * 16 + l15) * HEAD_DIM + ks * 32 + quad * 8);

    f32x4 O[2][6];
    float m_i[2], l_i[2];
    #pragma unroll
    for (int mf = 0; mf < 2; ++mf) {
        #pragma unroll
        for (int nf = 0; nf < 6; ++nf) O[mf][nf] = fzero();
        m_i[mf] = -INFINITY; l_i[mf] = 0.f;
    }

    for (int k0 = 0; k0 < SEQ - KTT; k0 += KTT)
        attn_step<true>(k0, kg, vg, Ps, lane, quad, l15, qf, O, m_i, l_i);
    attn_step<false>(576, kg, vg, Ps, lane, quad, l15, qf, O, m_i, l_i);

    #pragma unroll
    for (int mf = 0; mf < 2; ++mf) {
        #pragma unroll
        for (int r = 0; r < 4; ++r) {
            int row = q0 + mf * 16 + quad * 4 + r;
            if (row >= SEQ) continue;
            float lb = __shfl(l_i[mf], quad * 4 + r, 16);
            float il = 1.f / lb;
            size_t base = (size_t)(bb * SEQ + row) * HIDDEN + h * HEAD_DIM;
            #pragma unroll
            for (int nf = 0; nf < 6; ++nf) {
                int d = nf * 16 + l15;
                if (d < HEAD_DIM)
                    awsb[base + d] = f2bf(O[mf][nf][r] * il);
            }
        }
    }
}

// ---------------------------------------------------------------- launcher
extern "C" void kernel_launch(void* const* d_in, const int* in_sizes, int n_in,
                              void* d_out, int out_size, void* d_ws, size_t ws_size,
                              hipStream_t stream) {
    const float* hs    = (const float*)d_in[0];
    const float* w_qkv = (const float*)d_in[1];
    const float* b_qkv = (const float*)d_in[2];
    const float* w_o   = (const float*)d_in[3];
    const float* b_o   = (const float*)d_in[4];
    float* out = (float*)d_out;

    char* p = (char*)d_ws;
    auto alloc = [&](size_t bytes) {
        char* r = p; p += (bytes + 255) & ~(size_t)255; return r;
    };
    float*          cosb   = (float*)alloc((size_t)SEQ * RD * 4);
    float*          sinb   = (float*)alloc((size_t)SEQ * RD * 4);
    unsigned short* wqkv_t = (unsigned short*)alloc((size_t)NQKV_PAD * HIDDEN * 2);
    unsigned short* wo_t   = (unsigned short*)alloc((size_t)NOUT_PAD * HIDDEN * 2);
    unsigned short* hs_bf  = (unsigned short*)alloc((size_t)MPAD_ROWS * HIDDEN * 2);
    size_t fixed = (size_t)(p - (char*)d_ws);

    // per batch: q rows + K' fragments + V' fragments + attn rows
    size_t per_batch = (size_t)HEADS * SEQ * HEAD_DIM * 2
                     + 2ull * HEADS * FR_BH * 2
                     + (size_t)SEQ * HIDDEN * 2;
    size_t pads = 128ull * HEAD_DIM * 2 + 2ull * FR_BH * 2 + 256ull * HIDDEN * 2 + 16 * 256;
    size_t rem = (ws_size > fixed + pads) ? ws_size - fixed - pads : 0;
    int CB = (int)(rem / per_batch);
    if (CB < 1) CB = 1;
    if (CB > 32) CB = 32;

    unsigned short* qbuf  = (unsigned short*)alloc(((size_t)CB * HEADS * SEQ + 128) * HEAD_DIM * 2);
    unsigned short* kbuf  = (unsigned short*)alloc(((size_t)CB * HEADS + 1) * FR_BH * 2);
    unsigned short* vtbuf = (unsigned short*)alloc(((size_t)CB * HEADS + 1) * FR_BH * 2);
    unsigned short* awsb  = (unsigned short*)alloc(((size_t)CB * SEQ + 256) * HIDDEN * 2);

    rope_precompute<<<dim3(SEQ), dim3(64), 0, stream>>>(cosb, sinb);

    long nreal = (long)32 * SEQ * HIDDEN;
    long ntot  = (long)MPAD_ROWS * HIDDEN;
    conv_hs<<<dim3((unsigned)((ntot / 4 + 255) / 256)), 256, 0, stream>>>(hs, hs_bf, nreal, ntot);
    conv_wT<<<dim3(NQKV_PAD / 32, HIDDEN / 32), 256, 0, stream>>>(w_qkv, wqkv_t, HIDDEN, NQKV);
    conv_wT<<<dim3(NOUT_PAD / 32, HIDDEN / 32), 256, 0, stream>>>(w_o, wo_t, HIDDEN, HIDDEN);

    for (int b_off = 0; b_off < 32; b_off += CB) {
        int nb = (32 - b_off < CB) ? (32 - b_off) : CB;
        int M = nb * SEQ;

        dim3 g1(NQKV_PAD / 256, (M + 255) / 256);
        qkv_mfma<<<g1, 512, 0, stream>>>(hs_bf, wqkv_t, b_qkv, cosb, sinb,
                                         qbuf, kbuf, vtbuf, M, b_off * SEQ);
        dim3 g2((SEQ + 31) / 32, HEADS, nb);
        attn_mfma<<<g2, 64, 0, stream>>>(qbuf, kbuf, vtbuf, awsb);
        dim3 g3(NOUT_PAD / 256, (M + 255) / 256);
        out_mfma<<<g3, 512, 0, stream>>>(awsb, wo_t, b_o, out, M, b_off * SEQ);
    }
}